// Round 3
// baseline (314.505 us; speedup 1.0000x reference)
//
#include <hip/hip_runtime.h>
#include <hip/hip_bf16.h>
#include <math.h>

typedef __attribute__((ext_vector_type(4))) float f32x4;
typedef __attribute__((ext_vector_type(8))) short s16x8;

constexpr int Bc = 8;
constexpr int Nc = 2048;
constexpr int Hc = 128;
constexpr int ROWS = Bc * Nc;   // 16384

__device__ inline unsigned short f2bf(float f) {
  unsigned u = __float_as_uint(f);
  return (unsigned short)((u + 0x7fffu + ((u >> 16) & 1u)) >> 16);  // RNE
}
__device__ inline float bf2f(unsigned short b) {
  return __uint_as_float(((unsigned)b) << 16);
}

// ---------------------------------------------------------------------------
// k0: prep — Wt_hi/Wt_lo = split-bf16 of W, transposed to [h][k];
//     u1 = W@a[:H], u2 = W@a[H:]  (for wh1 = inp·u1 associativity trick)
// ---------------------------------------------------------------------------
__global__ void prep_kernel(const float* __restrict__ W, const float* __restrict__ a,
                            unsigned short* __restrict__ Wt_hi,
                            unsigned short* __restrict__ Wt_lo,
                            float* __restrict__ u1, float* __restrict__ u2) {
  const int t = threadIdx.x;
  {
    const int h = t >> 1, kb = (t & 1) * 64;
    for (int kk = 0; kk < 64; kk += 8) {
      unsigned uh[4], ul[4];
#pragma unroll
      for (int q = 0; q < 4; ++q) {
        const float w0 = W[(kb + kk + 2 * q) * 128 + h];
        const float w1 = W[(kb + kk + 2 * q + 1) * 128 + h];
        const unsigned short h0 = f2bf(w0), h1 = f2bf(w1);
        const unsigned short l0 = f2bf(w0 - bf2f(h0)), l1 = f2bf(w1 - bf2f(h1));
        uh[q] = (unsigned)h0 | ((unsigned)h1 << 16);
        ul[q] = (unsigned)l0 | ((unsigned)l1 << 16);
      }
      *(uint4*)(Wt_hi + h * 128 + kb + kk) = make_uint4(uh[0], uh[1], uh[2], uh[3]);
      *(uint4*)(Wt_lo + h * 128 + kb + kk) = make_uint4(ul[0], ul[1], ul[2], ul[3]);
    }
  }
  {
    const int k = t & 127;
    const float* av = a + ((t < 128) ? 0 : 128);
    float s = 0.f;
    for (int h = 0; h < 128; ++h) s = fmaf(W[k * 128 + h], av[h], s);
    if (t < 128) u1[k] = s; else u2[k] = s;
  }
}

// ---------------------------------------------------------------------------
// k1: Wh via split-bf16 MFMA (error ~2^-18 => effectively f32), emits
//     WhbfT[b][h][n] bf16 + exact-f32 wh1/wh2 via u1/u2 dots.
//     4 waves x 16 rows, N=128 full, K=128 in 4 steps. No LDS.
// ---------------------------------------------------------------------------
__global__ __launch_bounds__(256) void whmfma_kernel(
    const float* __restrict__ inp, const unsigned short* __restrict__ Wt_hi,
    const unsigned short* __restrict__ Wt_lo, const float* __restrict__ u1,
    const float* __restrict__ u2, unsigned short* __restrict__ WhbfT,
    float* __restrict__ Wh1, float* __restrict__ Wh2) {
  const int t = threadIdx.x, w_ = t >> 6, l = t & 63;
  const int r0 = blockIdx.x * 64 + w_ * 16;
  const int row = r0 + (l & 15);
  const int kg = (l >> 4) * 8;

  s16x8 ahi[4], alo[4];
  float p1 = 0.f, p2 = 0.f;
#pragma unroll
  for (int ks = 0; ks < 4; ++ks) {
    const float* xp = inp + (size_t)row * 128 + ks * 32 + kg;
    const f32x4 x0 = *(const f32x4*)xp;
    const f32x4 x1 = *(const f32x4*)(xp + 4);
    const f32x4 ua = *(const f32x4*)(u1 + ks * 32 + kg);
    const f32x4 ub = *(const f32x4*)(u1 + ks * 32 + kg + 4);
    const f32x4 va = *(const f32x4*)(u2 + ks * 32 + kg);
    const f32x4 vb = *(const f32x4*)(u2 + ks * 32 + kg + 4);
    s16x8 th, tl;
#pragma unroll
    for (int e = 0; e < 4; ++e) {
      p1 = fmaf(x0[e], ua[e], p1); p1 = fmaf(x1[e], ub[e], p1);
      p2 = fmaf(x0[e], va[e], p2); p2 = fmaf(x1[e], vb[e], p2);
      const unsigned short b0 = f2bf(x0[e]);
      const unsigned short b1 = f2bf(x1[e]);
      th[e] = (short)b0;     tl[e] = (short)f2bf(x0[e] - bf2f(b0));
      th[4 + e] = (short)b1; tl[4 + e] = (short)f2bf(x1[e] - bf2f(b1));
    }
    ahi[ks] = th; alo[ks] = tl;
  }
#pragma unroll
  for (int off = 32; off > 0; off >>= 4) {   // off = 32 then 16... (16,32 both needed)
    ;
  }
  p1 += __shfl_xor(p1, 16); p1 += __shfl_xor(p1, 32);
  p2 += __shfl_xor(p2, 16); p2 += __shfl_xor(p2, 32);
  if (l < 16) { Wh1[row] = p1; Wh2[row] = p2; }

  f32x4 acc[8];
  const f32x4 zero = {0.f, 0.f, 0.f, 0.f};
#pragma unroll
  for (int nb = 0; nb < 8; ++nb) acc[nb] = zero;

#pragma unroll
  for (int ks = 0; ks < 4; ++ks) {
#pragma unroll
    for (int nb = 0; nb < 8; ++nb) {
      const int bo = (nb * 16 + (l & 15)) * 128 + ks * 32 + kg;
      const s16x8 bh = *(const s16x8*)(Wt_hi + bo);
      const s16x8 bl = *(const s16x8*)(Wt_lo + bo);
      acc[nb] = __builtin_amdgcn_mfma_f32_16x16x32_bf16(ahi[ks], bh, acc[nb], 0, 0, 0);
      acc[nb] = __builtin_amdgcn_mfma_f32_16x16x32_bf16(alo[ks], bh, acc[nb], 0, 0, 0);
      acc[nb] = __builtin_amdgcn_mfma_f32_16x16x32_bf16(ahi[ks], bl, acc[nb], 0, 0, 0);
    }
  }

  // D: col = l&15 (h within 16), row = (l>>4)*4+rg (n, consecutive) -> 8B stores
  const int bq = r0 >> 11;
  const int nl = (r0 & 2047) + (l >> 4) * 4;
#pragma unroll
  for (int nb = 0; nb < 8; ++nb) {
    const unsigned q0 = (unsigned)f2bf(acc[nb][0]) | ((unsigned)f2bf(acc[nb][1]) << 16);
    const unsigned q1 = (unsigned)f2bf(acc[nb][2]) | ((unsigned)f2bf(acc[nb][3]) << 16);
    unsigned short* dst = WhbfT + ((size_t)(bq * 128 + nb * 16 + (l & 15))) * 2048 + nl;
    *(uint2*)dst = make_uint2(q0, q1);
  }
}

// ---------------------------------------------------------------------------
// k2: fused masked softmax + P@Wh + ELU. 4 waves SPLIT H (32 cols each),
// each wave walks all 32 j-tiles with depth-1 register double-buffering.
// No barriers, no merge. Scores computed redundantly x4 (cheap vs latency).
// ---------------------------------------------------------------------------
#define ALOAD(IT, AV, WV, VV) do {                                        \
    const int jb_ = (IT) * 64 + g8;                                       \
    AV[0] = *(const f32x4*)(Arow + jb_);                                  \
    AV[1] = *(const f32x4*)(Arow + jb_ + 4);                              \
    AV[2] = *(const f32x4*)(Arow + jb_ + 32);                             \
    AV[3] = *(const f32x4*)(Arow + jb_ + 36);                             \
    WV[0] = *(const f32x4*)(Wh2b + jb_);                                  \
    WV[1] = *(const f32x4*)(Wh2b + jb_ + 4);                              \
    WV[2] = *(const f32x4*)(Wh2b + jb_ + 32);                             \
    WV[3] = *(const f32x4*)(Wh2b + jb_ + 36);                             \
    const unsigned short* vp_ = Vb + (IT) * 64;                           \
    VV[0] = *(const s16x8*)vp_;                                           \
    VV[1] = *(const s16x8*)(vp_ + 32);                                    \
    VV[2] = *(const s16x8*)(vp_ + 16 * 2048);                             \
    VV[3] = *(const s16x8*)(vp_ + 16 * 2048 + 32);                        \
  } while (0)

#define BODY(IT, AVC, WVC, VVC, AVN, WVN, VVN) do {                       \
    if ((IT) < 31) ALOAD((IT) + 1, AVN, WVN, VVN);                        \
    const int jb0 = (IT) * 64;                                            \
    float s[16]; float tm = -3e30f;                                       \
    _Pragma("unroll") for (int idx = 0; idx < 16; ++idx) {                \
      const int j = jb0 + ((idx >> 3) * 32) + g8 + (idx & 7);             \
      const float aval = AVC[idx >> 2][idx & 3];                          \
      const float raw  = wh1r + WVC[idx >> 2][idx & 3];                   \
      const float lr   = fmaxf(raw, 0.2f * raw);                         \
      const float mult = aval + ((j == irow) ? 1.f : 0.f);                \
      const float sv   = (mult > 0.f) ? mult * lr : -2e30f;               \
      s[idx] = sv; tm = fmaxf(tm, sv);                                    \
    }                                                                     \
    tm = fmaxf(tm, __shfl_xor(tm, 16));                                   \
    tm = fmaxf(tm, __shfl_xor(tm, 32));                                   \
    const float mnew = (tm > m + 8.f) ? tm : m;                           \
    if (__ballot(mnew != m)) {                                            \
      const float alpha = __expf(m - mnew);                               \
      lsum *= alpha;                                                      \
      const int rb = (l >> 4) * 4;                                        \
      const float a0 = __shfl(alpha, rb),     a1 = __shfl(alpha, rb + 1); \
      const float a2 = __shfl(alpha, rb + 2), a3 = __shfl(alpha, rb + 3); \
      acc0[0] *= a0; acc0[1] *= a1; acc0[2] *= a2; acc0[3] *= a3;         \
      acc1[0] *= a0; acc1[1] *= a1; acc1[2] *= a2; acc1[3] *= a3;         \
      m = mnew;                                                           \
    }                                                                     \
    float p[16]; float tsum = 0.f;                                        \
    _Pragma("unroll") for (int idx = 0; idx < 16; ++idx) {                \
      p[idx] = __expf(s[idx] - m); tsum += p[idx];                        \
    }                                                                     \
    tsum += __shfl_xor(tsum, 16); tsum += __shfl_xor(tsum, 32);           \
    lsum += tsum;                                                         \
    union { unsigned u[4]; s16x8 v; } pk0, pk1;                           \
    _Pragma("unroll") for (int q = 0; q < 4; ++q) {                       \
      asm("v_cvt_pk_bf16_f32 %0, %1, %2"                                  \
          : "=v"(pk0.u[q]) : "v"(p[2 * q]), "v"(p[2 * q + 1]));           \
      asm("v_cvt_pk_bf16_f32 %0, %1, %2"                                  \
          : "=v"(pk1.u[q]) : "v"(p[8 + 2 * q]), "v"(p[9 + 2 * q]));       \
    }                                                                     \
    acc0 = __builtin_amdgcn_mfma_f32_16x16x32_bf16(pk0.v, VVC[0], acc0, 0, 0, 0); \
    acc0 = __builtin_amdgcn_mfma_f32_16x16x32_bf16(pk1.v, VVC[1], acc0, 0, 0, 0); \
    acc1 = __builtin_amdgcn_mfma_f32_16x16x32_bf16(pk0.v, VVC[2], acc1, 0, 0, 0); \
    acc1 = __builtin_amdgcn_mfma_f32_16x16x32_bf16(pk1.v, VVC[3], acc1, 0, 0, 0); \
  } while (0)

__global__ __launch_bounds__(256, 2) void attn_kernel(
    const float* __restrict__ A, const unsigned short* __restrict__ WhbfT,
    const float* __restrict__ Wh1, const float* __restrict__ Wh2,
    float* __restrict__ out) {
  const int t = threadIdx.x, w_ = t >> 6, l = t & 63;
  const int bid = blockIdx.x;            // 16-row group id (0..1023)
  const int b = bid >> 7;                // batch
  const int g8 = (l >> 4) * 8;
  const int lrow = l & 15;
  const int irow = (bid & 127) * 16 + lrow;   // row within batch (diag check)

  const float* Arow = A + ((size_t)bid * 16 + lrow) * 2048;
  const float* Wh2b = Wh2 + (size_t)b * 2048;
  const float wh1r = Wh1[(size_t)bid * 16 + lrow];
  // this wave's V base: h = w_*32 + lrow (nb-local 0); +16*2048 for nb-local 1
  const unsigned short* Vb =
      WhbfT + ((size_t)(b * 128 + w_ * 32 + lrow)) * 2048 + g8;

  f32x4 acc0 = {0.f, 0.f, 0.f, 0.f};
  f32x4 acc1 = {0.f, 0.f, 0.f, 0.f};
  float m = -1e30f, lsum = 0.f;

  f32x4 avA[4], wvA[4], avB[4], wvB[4];
  s16x8 vvA[4], vvB[4];
  ALOAD(0, avA, wvA, vvA);

  for (int it2 = 0; it2 < 16; ++it2) {
    BODY(2 * it2,     avA, wvA, vvA, avB, wvB, vvB);
    BODY(2 * it2 + 1, avB, wvB, vvB, avA, wvA, vvA);
  }

  // epilogue: scale by 1/l, ELU, direct store of this wave's 32 h-columns
  const int rb = (l >> 4) * 4;
  float linv[4];
#pragma unroll
  for (int rg = 0; rg < 4; ++rg) linv[rg] = 1.f / __shfl(lsum, rb + rg);

  float* outp = out + (size_t)bid * 16 * 128 + w_ * 32 + lrow;
#pragma unroll
  for (int rg = 0; rg < 4; ++rg) {
    float v0 = acc0[rg] * linv[rg];
    float v1 = acc1[rg] * linv[rg];
    v0 = (v0 > 0.f) ? v0 : expm1f(v0);
    v1 = (v1 > 0.f) ? v1 : expm1f(v1);
    outp[(size_t)(rb + rg) * 128] = v0;
    outp[(size_t)(rb + rg) * 128 + 16] = v1;
  }
}

extern "C" void kernel_launch(void* const* d_in, const int* in_sizes, int n_in,
                              void* d_out, int out_size, void* d_ws, size_t ws_size,
                              hipStream_t stream) {
  const float* inp = (const float*)d_in[0];   // [B,N,H]
  const float* A   = (const float*)d_in[1];   // [B,N,N]
  const float* W   = (const float*)d_in[2];   // [H,H]
  const float* a   = (const float*)d_in[3];   // [2H,1]
  float* out = (float*)d_out;

  char* ws = (char*)d_ws;
  unsigned short* WhbfT = (unsigned short*)ws;               ws += (size_t)Bc * Hc * Nc * 2;  // 4MB
  float* Wh1 = (float*)ws;                                   ws += ROWS * 4;                  // 64KB
  float* Wh2 = (float*)ws;                                   ws += ROWS * 4;                  // 64KB
  unsigned short* Wt_hi = (unsigned short*)ws;               ws += 128 * 128 * 2;             // 32KB
  unsigned short* Wt_lo = (unsigned short*)ws;               ws += 128 * 128 * 2;             // 32KB
  float* u1 = (float*)ws;                                    ws += 128 * 4;
  float* u2 = (float*)ws;

  prep_kernel<<<dim3(1), dim3(256), 0, stream>>>(W, a, Wt_hi, Wt_lo, u1, u2);
  whmfma_kernel<<<dim3(ROWS / 64), dim3(256), 0, stream>>>(inp, Wt_hi, Wt_lo, u1, u2,
                                                           WhbfT, Wh1, Wh2);
  attn_kernel<<<dim3(ROWS / 16), dim3(256), 0, stream>>>(A, WhbfT, Wh1, Wh2, out);
}

// Round 5
// 228.363 us; speedup vs baseline: 1.3772x; 1.3772x over previous
//
#include <hip/hip_runtime.h>
#include <hip/hip_bf16.h>
#include <math.h>

typedef __attribute__((ext_vector_type(4))) float f32x4;
typedef __attribute__((ext_vector_type(8))) short s16x8;

constexpr int Nc = 2048;
constexpr int Hc = 128;
constexpr int ROWS = 8 * 2048;

__device__ __forceinline__ unsigned short f2bf(float f) {
  unsigned u = __float_as_uint(f);
  return (unsigned short)((u + 0x7fffu + ((u >> 16) & 1u)) >> 16);  // RNE
}
__device__ __forceinline__ float bf2f(unsigned short b) {
  return __uint_as_float(((unsigned)b) << 16);
}

typedef __attribute__((address_space(3))) unsigned u32_lds;
typedef __attribute__((address_space(1))) const unsigned u32_glb;
__device__ __forceinline__ void stage16(const void* g, void* l) {
  __builtin_amdgcn_global_load_lds((u32_glb*)g, (u32_lds*)l, 16, 0, 0);
}

// ---------------------------------------------------------------------------
// k0: prep — split-bf16 W, transposed into MFMA-B-frag-friendly layout:
//     Wt[(k>>3)][h][k&7]  (bf16). Grid 64 x 256, fully parallel.
// ---------------------------------------------------------------------------
__global__ void prep_kernel(const float* __restrict__ W,
                            unsigned short* __restrict__ Wt_hi,
                            unsigned short* __restrict__ Wt_lo) {
  const int id = blockIdx.x * 256 + threadIdx.x;   // 0..16383 = k*128+h
  const int k = id >> 7, h = id & 127;
  const float w = W[id];
  const unsigned short hi = f2bf(w);
  const unsigned short lo = f2bf(w - bf2f(hi));
  const int off = ((k >> 3) * 128 + h) * 8 + (k & 7);
  Wt_hi[off] = hi;
  Wt_lo[off] = lo;
}

// ---------------------------------------------------------------------------
// k1: Wh via split-bf16 MFMA (3-term, ~f32 accuracy). Emits:
//     Vsw[b][jt(32)][jg(8)][h(128)][8j] bf16  (attn-friendly V layout)
//     Wh1/Wh2 f32 (row dots with a1/a2, computed from acc fragments)
// ---------------------------------------------------------------------------
__global__ __launch_bounds__(256) void whmfma_kernel(
    const float* __restrict__ inp, const unsigned short* __restrict__ Wt_hi,
    const unsigned short* __restrict__ Wt_lo, const float* __restrict__ a,
    unsigned short* __restrict__ Vsw, float* __restrict__ Wh1,
    float* __restrict__ Wh2) {
  const int t = threadIdx.x, w_ = t >> 6, l = t & 63;
  const int lrow = l & 15, kq = l >> 4;
  const int r0 = blockIdx.x * 64 + w_ * 16;
  const int row = r0 + lrow;

  s16x8 ahi[4], alo[4];
#pragma unroll
  for (int ks = 0; ks < 4; ++ks) {
    const float* xp = inp + (size_t)row * 128 + ks * 32 + kq * 8;
    const f32x4 x0 = *(const f32x4*)xp;
    const f32x4 x1 = *(const f32x4*)(xp + 4);
    s16x8 th, tl;
#pragma unroll
    for (int e = 0; e < 4; ++e) {
      const unsigned short b0 = f2bf(x0[e]), b1 = f2bf(x1[e]);
      th[e] = (short)b0;       tl[e] = (short)f2bf(x0[e] - bf2f(b0));
      th[4 + e] = (short)b1;   tl[4 + e] = (short)f2bf(x1[e] - bf2f(b1));
    }
    ahi[ks] = th; alo[ks] = tl;
  }

  f32x4 acc[8];
#pragma unroll
  for (int nb = 0; nb < 8; ++nb) acc[nb] = (f32x4){0.f, 0.f, 0.f, 0.f};

#pragma unroll
  for (int ks = 0; ks < 4; ++ks) {
#pragma unroll
    for (int nb = 0; nb < 8; ++nb) {
      const size_t bo = ((size_t)(ks * 4 + kq) * 128 + nb * 16 + lrow) * 8;
      const s16x8 bh = *(const s16x8*)(Wt_hi + bo);
      const s16x8 bl = *(const s16x8*)(Wt_lo + bo);
      acc[nb] = __builtin_amdgcn_mfma_f32_16x16x32_bf16(ahi[ks], bh, acc[nb], 0, 0, 0);
      acc[nb] = __builtin_amdgcn_mfma_f32_16x16x32_bf16(alo[ks], bh, acc[nb], 0, 0, 0);
      acc[nb] = __builtin_amdgcn_mfma_f32_16x16x32_bf16(ahi[ks], bl, acc[nb], 0, 0, 0);
    }
  }

  // Wh1/Wh2 = Wh row-dot a1/a2 from acc frags (h = nb*16+lrow, node = kq*4+rg)
  float a1v[8], a2v[8];
#pragma unroll
  for (int nb = 0; nb < 8; ++nb) {
    a1v[nb] = a[nb * 16 + lrow];
    a2v[nb] = a[128 + nb * 16 + lrow];
  }
#pragma unroll
  for (int rg = 0; rg < 4; ++rg) {
    float p1 = 0.f, p2 = 0.f;
#pragma unroll
    for (int nb = 0; nb < 8; ++nb) {
      p1 = fmaf(acc[nb][rg], a1v[nb], p1);
      p2 = fmaf(acc[nb][rg], a2v[nb], p2);
    }
#pragma unroll
    for (int off = 1; off < 16; off <<= 1) {
      p1 += __shfl_xor(p1, off);
      p2 += __shfl_xor(p2, off);
    }
    if (lrow == 0) {
      const int node = r0 + kq * 4 + rg;
      Wh1[node] = p1;
      Wh2[node] = p2;
    }
  }

  // Vsw write: node_local = w_*16 + kq*4 + rg; jg = nl>>3, jj = nl&7
  const int b = r0 >> 11, jt = (r0 >> 6) & 31;
  unsigned short* __restrict__ vbase = Vsw + (size_t)(b * 32 + jt) * (8 * 128 * 8);
  const int nl0 = w_ * 16 + kq * 4;
  const int jg = nl0 >> 3, j0 = nl0 & 7;
#pragma unroll
  for (int nb = 0; nb < 8; ++nb) {
    unsigned q0, q1;
    asm("v_cvt_pk_bf16_f32 %0, %1, %2" : "=v"(q0) : "v"(acc[nb][0]), "v"(acc[nb][1]));
    asm("v_cvt_pk_bf16_f32 %0, %1, %2" : "=v"(q1) : "v"(acc[nb][2]), "v"(acc[nb][3]));
    *(uint2*)(vbase + ((size_t)jg * 128 + nb * 16 + lrow) * 8 + j0) = make_uint2(q0, q1);
  }
}

// ---------------------------------------------------------------------------
// k2: fused masked softmax + P@Wh + ELU.
// Block = 4 waves x 16 q-rows; j in 8 chunks of 256; wave w_ takes sub-tile
// w_*64 of each chunk (no redundancy). A+Wh2 staged to LDS by global_load_lds
// (coalesced streams, XOR-swizzled source), double-buffered, one barrier/chunk.
// V from Vsw (256B-contiguous frag loads, L2-resident). R2-style merge.
// ---------------------------------------------------------------------------
__global__ __launch_bounds__(256, 3) void attn_kernel(
    const float* __restrict__ A, const unsigned short* __restrict__ Vsw,
    const float* __restrict__ Wh1, const float* __restrict__ Wh2,
    float* __restrict__ out) {
  __shared__ union {
    struct { float Ab[2][16][256]; float w2[2][256]; } st;                    // 34KB
    struct { float m[64]; float l[64]; float invl[16]; float a4[4][16][132]; } mg;
  } sm;

  const int t = threadIdx.x, w_ = t >> 6, l = t & 63;
  const int lrow = l & 15, lq = l >> 4, g8 = lq * 8;
  const int bid = (blockIdx.x & 7) * 128 + (blockIdx.x >> 3);  // XCD-chunked (1024%8==0)
  const int b = bid >> 7;
  const int irow = (bid & 127) * 16 + lrow;

  const float* __restrict__ Abase = A + (size_t)bid * 16 * 2048;
  const float* __restrict__ Wh2b = Wh2 + (size_t)b * 2048;
  const float wh1r = Wh1[(size_t)bid * 16 + lrow];
  const unsigned short* __restrict__ Vb = Vsw + (size_t)b * (32 * 8 * 128 * 8);
  const size_t vlane = (size_t)(lq * 128 + lrow) * 8;

  // prologue: stage chunk 0 -> buf 0 (wave w_ stages rows w_*4..+3)
#pragma unroll
  for (int rr = 0; rr < 4; ++rr) {
    const int r = w_ * 4 + rr;
    stage16(Abase + (size_t)r * 2048 + ((l ^ (r & 7)) << 2), &sm.st.Ab[0][r][0]);
  }
  if (w_ == 0) stage16(Wh2b + l * 4, &sm.st.w2[0][0]);

  f32x4 acc[8];
#pragma unroll
  for (int nb = 0; nb < 8; ++nb) acc[nb] = (f32x4){0.f, 0.f, 0.f, 0.f};
  float m = -1e30f, lsum = 0.f;

  for (int c = 0; c < 8; ++c) {
    __syncthreads();   // drains vmcnt(0): chunk c's stages complete
    const int buf = c & 1;
    if (c < 7) {       // stage chunk c+1 into other buffer (hidden under compute)
#pragma unroll
      for (int rr = 0; rr < 4; ++rr) {
        const int r = w_ * 4 + rr;
        stage16(Abase + (size_t)r * 2048 + (c + 1) * 256 + ((l ^ (r & 7)) << 2),
                &sm.st.Ab[buf ^ 1][r][0]);
      }
      if (w_ == 0) stage16(Wh2b + (c + 1) * 256 + l * 4, &sm.st.w2[buf ^ 1][0]);
    }

    const int jb_loc = w_ * 64;
    const int jb_glob = c * 256 + jb_loc;
    const unsigned short* __restrict__ Vt = Vb + (size_t)(c * 4 + w_) * (8 * 128 * 8);

    // V first half (nb 0-3, both k-halves): 256B-contiguous per 16 lanes
    s16x8 v0[4], v1[4];
#pragma unroll
    for (int nb = 0; nb < 4; ++nb) {
      v0[nb] = *(const s16x8*)(Vt + vlane + nb * 128);
      v1[nb] = *(const s16x8*)(Vt + vlane + 4096 + nb * 128);
    }

    // A-frag (swizzled) + wh2-frag from LDS
    f32x4 av[4], wv[4];
    const int c0 = (jb_loc + g8) >> 2;
#pragma unroll
    for (int q = 0; q < 4; ++q) {
      const int cq = c0 + (q & 1) + (q >> 1) * 8;
      av[q] = *(const f32x4*)&sm.st.Ab[buf][lrow][(cq ^ (lrow & 7)) << 2];
      wv[q] = *(const f32x4*)&sm.st.w2[buf][jb_loc + g8 + (q & 1) * 4 + (q >> 1) * 32];
    }

    float s[16];
    float tm = -3e30f;
#pragma unroll
    for (int idx = 0; idx < 16; ++idx) {
      const int j = jb_glob + (idx >> 3) * 32 + g8 + (idx & 7);
      const float aval = av[idx >> 2][idx & 3];
      const float raw = wh1r + wv[idx >> 2][idx & 3];
      const float lr = fmaxf(raw, 0.2f * raw);
      const float mult = aval + ((j == irow) ? 1.f : 0.f);
      const float sv = (mult > 0.f) ? mult * lr : -2e30f;
      s[idx] = sv;
      tm = fmaxf(tm, sv);
    }
    tm = fmaxf(tm, __shfl_xor(tm, 16));
    tm = fmaxf(tm, __shfl_xor(tm, 32));
    const float mnew = (tm > m + 8.f) ? tm : m;   // defer-max (THR=8)
    if (__ballot(mnew != m)) {
      const float alpha = __expf(m - mnew);       // ==1 for unchanged rows
      lsum *= alpha;
      const int rb4 = lq * 4;
      const float a0 = __shfl(alpha, rb4);
      const float a1 = __shfl(alpha, rb4 + 1);
      const float a2 = __shfl(alpha, rb4 + 2);
      const float a3 = __shfl(alpha, rb4 + 3);
#pragma unroll
      for (int nb = 0; nb < 8; ++nb) {
        acc[nb][0] *= a0; acc[nb][1] *= a1; acc[nb][2] *= a2; acc[nb][3] *= a3;
      }
      m = mnew;
    }

    float p[16];
    float tsum = 0.f;
#pragma unroll
    for (int idx = 0; idx < 16; ++idx) {
      p[idx] = __expf(s[idx] - m);   // masked: exp(-huge)=0
      tsum += p[idx];
    }
    tsum += __shfl_xor(tsum, 16);
    tsum += __shfl_xor(tsum, 32);
    lsum += tsum;

    union { unsigned u[4]; s16x8 v; } pk0, pk1;
#pragma unroll
    for (int q = 0; q < 4; ++q) {
      asm("v_cvt_pk_bf16_f32 %0, %1, %2" : "=v"(pk0.u[q]) : "v"(p[2 * q]), "v"(p[2 * q + 1]));
      asm("v_cvt_pk_bf16_f32 %0, %1, %2" : "=v"(pk1.u[q]) : "v"(p[8 + 2 * q]), "v"(p[9 + 2 * q]));
    }

    // V second half
    s16x8 v2[4], v3[4];
#pragma unroll
    for (int nb = 0; nb < 4; ++nb) {
      v2[nb] = *(const s16x8*)(Vt + vlane + (nb + 4) * 128);
      v3[nb] = *(const s16x8*)(Vt + vlane + 4096 + (nb + 4) * 128);
    }
#pragma unroll
    for (int nb = 0; nb < 4; ++nb) {
      acc[nb] = __builtin_amdgcn_mfma_f32_16x16x32_bf16(pk0.v, v0[nb], acc[nb], 0, 0, 0);
      acc[nb] = __builtin_amdgcn_mfma_f32_16x16x32_bf16(pk1.v, v1[nb], acc[nb], 0, 0, 0);
    }
#pragma unroll
    for (int nb = 0; nb < 4; ++nb) {
      acc[nb + 4] = __builtin_amdgcn_mfma_f32_16x16x32_bf16(pk0.v, v2[nb], acc[nb + 4], 0, 0, 0);
      acc[nb + 4] = __builtin_amdgcn_mfma_f32_16x16x32_bf16(pk1.v, v3[nb], acc[nb + 4], 0, 0, 0);
    }
  }

  // ---------------- merge epilogue (LDS reused via union) ----------------
  __syncthreads();
  if (l < 16) { sm.mg.m[w_ * 16 + l] = m; sm.mg.l[w_ * 16 + l] = lsum; }
  __syncthreads();

  if (t < 16) {   // thread t computes 1/l* for row t
    const float m0 = sm.mg.m[t], m1 = sm.mg.m[16 + t];
    const float m2 = sm.mg.m[32 + t], m3 = sm.mg.m[48 + t];
    const float ms = fmaxf(fmaxf(m0, m1), fmaxf(m2, m3));
    const float ls = sm.mg.l[t] * __expf(m0 - ms) + sm.mg.l[16 + t] * __expf(m1 - ms)
                   + sm.mg.l[32 + t] * __expf(m2 - ms) + sm.mg.l[48 + t] * __expf(m3 - ms);
    sm.mg.invl[t] = 1.f / ls;
  }
  float beta[4];
#pragma unroll
  for (int rg = 0; rg < 4; ++rg) {
    const int rd = lq * 4 + rg;
    const float m0 = sm.mg.m[rd], m1 = sm.mg.m[16 + rd];
    const float m2 = sm.mg.m[32 + rd], m3 = sm.mg.m[48 + rd];
    const float ms = fmaxf(fmaxf(m0, m1), fmaxf(m2, m3));
    beta[rg] = __expf(sm.mg.m[w_ * 16 + rd] - ms);
  }
#pragma unroll
  for (int nb = 0; nb < 8; ++nb)
#pragma unroll
    for (int rg = 0; rg < 4; ++rg)
      sm.mg.a4[w_][lq * 4 + rg][nb * 16 + lrow] = acc[nb][rg] * beta[rg];
  __syncthreads();

  const int h = w_ * 32 + (l & 31);
  float* __restrict__ outp = out + (size_t)bid * 16 * 128;
#pragma unroll
  for (int i = 0; i < 8; ++i) {
    const int r = (l >> 5) + 2 * i;
    float v = (sm.mg.a4[0][r][h] + sm.mg.a4[1][r][h] +
               sm.mg.a4[2][r][h] + sm.mg.a4[3][r][h]) * sm.mg.invl[r];
    outp[(size_t)r * 128 + h] = (v > 0.f) ? v : expm1f(v);
  }
}

extern "C" void kernel_launch(void* const* d_in, const int* in_sizes, int n_in,
                              void* d_out, int out_size, void* d_ws, size_t ws_size,
                              hipStream_t stream) {
  const float* inp = (const float*)d_in[0];   // [B,N,H]
  const float* A   = (const float*)d_in[1];   // [B,N,N]
  const float* W   = (const float*)d_in[2];   // [H,H]
  const float* a   = (const float*)d_in[3];   // [2H,1]
  float* out = (float*)d_out;

  char* ws = (char*)d_ws;
  unsigned short* Vsw = (unsigned short*)ws;  ws += (size_t)8 * 32 * 8 * 128 * 8 * 2;  // 4MB
  float* Wh1 = (float*)ws;                    ws += (size_t)ROWS * 4;
  float* Wh2 = (float*)ws;                    ws += (size_t)ROWS * 4;
  unsigned short* Wt_hi = (unsigned short*)ws; ws += 128 * 128 * 2;
  unsigned short* Wt_lo = (unsigned short*)ws; ws += 128 * 128 * 2;

  prep_kernel<<<dim3(64), dim3(256), 0, stream>>>(W, Wt_hi, Wt_lo);
  whmfma_kernel<<<dim3(256), dim3(256), 0, stream>>>(inp, Wt_hi, Wt_lo, a, Vsw, Wh1, Wh2);
  attn_kernel<<<dim3(1024), dim3(256), 0, stream>>>(A, Vsw, Wh1, Wh2, out);
}